// Round 6
// baseline (188.355 us; speedup 1.0000x reference)
//
#include <hip/hip_runtime.h>
#include <math.h>

#define N_BINS 15
#define LOG2E 1.4426950408889634f

// --- DPP helpers: full 16-lane butterfly with xor-span {1,2,7,15} ---
// 0xB1 = quad_perm[1,0,3,2] (xor1), 0x4E = quad_perm[2,3,0,1] (xor2),
// 0x141 = row_half_mirror (xor7), 0x140 = row_mirror (xor15).
template <int CTRL>
__device__ __forceinline__ float dpp_f(float x) {
    return __int_as_float(__builtin_amdgcn_update_dpp(
        0, __float_as_int(x), CTRL, 0xF, 0xF, true));
}
template <int CTRL>
__device__ __forceinline__ int dpp_i(int x) {
    return __builtin_amdgcn_update_dpp(0, x, CTRL, 0xF, 0xF, true);
}

__device__ __forceinline__ float rowmax16(float m) {
    m = fmaxf(m, dpp_f<0xB1>(m));
    m = fmaxf(m, dpp_f<0x4E>(m));
    m = fmaxf(m, dpp_f<0x141>(m));
    m = fmaxf(m, dpp_f<0x140>(m));
    return m;
}
__device__ __forceinline__ float rowsum16(float x) {
    x += dpp_f<0xB1>(x);
    x += dpp_f<0x4E>(x);
    x += dpp_f<0x141>(x);
    x += dpp_f<0x140>(x);
    return x;
}
__device__ __forceinline__ int rowmin16(int x) {
    x = min(x, dpp_i<0xB1>(x));
    x = min(x, dpp_i<0x4E>(x));
    x = min(x, dpp_i<0x141>(x));
    x = min(x, dpp_i<0x140>(x));
    return x;
}

// One row held by a 16-lane group; lane holds cols colbase..+3 and 64+colbase..+3.
__device__ __forceinline__ void process_row(
    float4 ca, float4 cb, int colbase, bool leader, int lab, bool valid,
    float* s_conf, float* s_acc)
{
    // row max: v_max3 tree + 4-step DPP
    const float t0 = fmaxf(fmaxf(ca.x, ca.y), ca.z);
    const float t1 = fmaxf(fmaxf(ca.w, cb.x), cb.y);
    const float t2 = fmaxf(fmaxf(cb.z, cb.w), t0);
    float m = fmaxf(t1, t2);
    m = rowmax16(m);

    // sum(exp2(v*log2e - m*log2e))
    const float nmL = -m * LOG2E;
    float e0 = __builtin_amdgcn_exp2f(fmaf(ca.x, LOG2E, nmL));
    float e1 = __builtin_amdgcn_exp2f(fmaf(ca.y, LOG2E, nmL));
    float e2 = __builtin_amdgcn_exp2f(fmaf(ca.z, LOG2E, nmL));
    float e3 = __builtin_amdgcn_exp2f(fmaf(ca.w, LOG2E, nmL));
    float e4 = __builtin_amdgcn_exp2f(fmaf(cb.x, LOG2E, nmL));
    float e5 = __builtin_amdgcn_exp2f(fmaf(cb.y, LOG2E, nmL));
    float e6 = __builtin_amdgcn_exp2f(fmaf(cb.z, LOG2E, nmL));
    float e7 = __builtin_amdgcn_exp2f(fmaf(cb.w, LOG2E, nmL));
    float e = ((e0 + e1) + (e2 + e3)) + ((e4 + e5) + (e6 + e7));
    e = rowsum16(e);

    // deferred argmax (first occurrence): candidate index or INF, min-reduce
    const int INF = 0x7FFFFFFF;
    const int c0 = (ca.x == m) ? colbase      : INF;
    const int c1 = (ca.y == m) ? colbase + 1  : INF;
    const int c2 = (ca.z == m) ? colbase + 2  : INF;
    const int c3 = (ca.w == m) ? colbase + 3  : INF;
    const int c4 = (cb.x == m) ? colbase + 64 : INF;
    const int c5 = (cb.y == m) ? colbase + 65 : INF;
    const int c6 = (cb.z == m) ? colbase + 66 : INF;
    const int c7 = (cb.w == m) ? colbase + 67 : INF;
    const int m1 = min(min(c0, c1), c2);
    const int m2 = min(min(c3, c4), c5);
    const int m3 = min(min(c6, c7), m1);
    int idx = min(m2, m3);
    idx = rowmin16(idx);

    if (valid && leader) {
        const float conf = __builtin_amdgcn_rcpf(e);
        int bin = (int)ceilf(conf * (float)N_BINS) - 1;
        bin = min(max(bin, 0), N_BINS - 1);
        atomicAdd(&s_conf[bin], conf);
        atomicAdd(&s_acc[bin], (idx == lab) ? 1.0f : 0.0f);
    }
}

// Round-4 proven structure: 16 lanes/row, two 4-row tiles (8 rows) per wave
// per iteration, compiler-managed depth-1 prefetch, u32 incremental byte
// addressing, branch-free main loop. NO forced min-occupancy (round 5's
// __launch_bounds__(256,8) caused scratch spills and a 60us regression).
// Finish is fused via last-block ticket; counts cancel algebraically:
// sum_b gap_b*cnt_b/n == sum_b |conf_sum_b - acc_sum_b| / n.
__global__ __launch_bounds__(256) void ece_fused(
    const float* __restrict__ logits,
    const int* __restrict__ labels,
    int n,
    double* __restrict__ conf_sum,
    double* __restrict__ acc_sum,
    unsigned int* __restrict__ ticket,
    float* __restrict__ out)
{
    __shared__ float s_conf[N_BINS];
    __shared__ float s_acc[N_BINS];
    __shared__ double s_term[N_BINS];
    __shared__ bool s_last;

    const int t = threadIdx.x;
    if (t < N_BINS) { s_conf[t] = 0.f; s_acc[t] = 0.f; }
    __syncthreads();

    const int lane = t & 63;
    const int g    = lane >> 4;          // row within 4-row tile
    const int s    = lane & 15;          // sublane within 16-lane group
    const bool leader = (s == 0);
    const int colbase = 4 * s;

    const int wid = (blockIdx.x << 2) | (t >> 6);   // wave id
    const int nw  = gridDim.x << 2;                 // total waves
    const unsigned rstep = (unsigned)nw * 8u;       // rows per grid iteration
    const unsigned bstep = rstep * 512u;            // bytes per grid iteration

    // iterations where ALL 8 rows of this wave are < n
    int nfull = 0;
    {
        const int lim = n - 8 - wid * 8;
        if (lim >= 0) nfull = lim / (int)rstep + 1;
    }

    const char* __restrict__ Lg = (const char*)logits;
    const unsigned row0 = (unsigned)(wid * 8 + g);      // tile-A row, iter 0
    unsigned off  = row0 * 512u + (unsigned)s * 16u;    // tile-A byte offset
    unsigned lrow = row0;                               // label index

    float4 a0, a1, b0, b1;
    if (nfull > 0) {
        a0 = *(const float4*)(Lg + off);
        a1 = *(const float4*)(Lg + off + 256u);
        b0 = *(const float4*)(Lg + off + 2048u);
        b1 = *(const float4*)(Lg + off + 2304u);
    }

    for (int k = 0; k < nfull; ++k) {
        const int labA = labels[lrow];
        const int labB = labels[lrow + 4u];
        const float4 ca0 = a0, ca1 = a1, cb0 = b0, cb1 = b1;

        const unsigned noff = off + bstep;
        if (k + 1 < nfull) {   // wave-uniform scalar branch
            a0 = *(const float4*)(Lg + noff);
            a1 = *(const float4*)(Lg + noff + 256u);
            b0 = *(const float4*)(Lg + noff + 2048u);
            b1 = *(const float4*)(Lg + noff + 2304u);
        }

        process_row(ca0, ca1, colbase, leader, labA, true, s_conf, s_acc);
        process_row(cb0, cb1, colbase, leader, labB, true, s_conf, s_acc);

        off = noff;
        lrow += rstep;
    }

    // generic guarded tail (at most one iteration; empty for n = 1e6)
    {
        const unsigned tbase = (unsigned)(wid * 8) + (unsigned)nfull * rstep;
        if (tbase < (unsigned)n) {
            const unsigned rA = tbase + (unsigned)g;
            const unsigned rB = rA + 4u;
            const bool vA = rA < (unsigned)n;
            const bool vB = rB < (unsigned)n;
            const unsigned cA = vA ? rA : (unsigned)(n - 1);
            const unsigned cB = vB ? rB : (unsigned)(n - 1);
            const unsigned oA = cA * 512u + (unsigned)s * 16u;
            const unsigned oB = cB * 512u + (unsigned)s * 16u;
            float4 ta0 = *(const float4*)(Lg + oA);
            float4 ta1 = *(const float4*)(Lg + oA + 256u);
            float4 tb0 = *(const float4*)(Lg + oB);
            float4 tb1 = *(const float4*)(Lg + oB + 256u);
            const int labA = vA ? labels[rA] : -1;
            const int labB = vB ? labels[rB] : -1;
            process_row(ta0, ta1, colbase, leader, labA, vA, s_conf, s_acc);
            process_row(tb0, tb1, colbase, leader, labB, vB, s_conf, s_acc);
        }
    }

    __syncthreads();
    // flush block-local histogram (conf>0 iff bin nonempty)
    if (t < N_BINS && s_conf[t] != 0.f) {
        atomicAdd(&conf_sum[t], (double)s_conf[t]);
        atomicAdd(&acc_sum[t], (double)s_acc[t]);
    }
    __syncthreads();   // this block's flush atomics issued by all lanes

    if (t == 0) {
        __threadfence();                       // order flush before ticket
        const unsigned prev = atomicAdd(ticket, 1u);
        s_last = (prev == (unsigned)(gridDim.x - 1));
    }
    __syncthreads();

    if (s_last) {
        // all other blocks' flushes happened-before their ticket adds;
        // read via atomic RMW (device-scope coherent, bypasses L1).
        if (t < N_BINS) {
            const double cs = atomicAdd(&conf_sum[t], 0.0);
            const double as = atomicAdd(&acc_sum[t], 0.0);
            s_term[t] = fabs(cs - as) / (double)n;
        }
        __syncthreads();
        if (t == 0) {
            double ece = 0.0;
            #pragma unroll
            for (int b = 0; b < N_BINS; ++b) ece += s_term[b];
            out[0] = (float)ece;
        }
    }
}

extern "C" void kernel_launch(void* const* d_in, const int* in_sizes, int n_in,
                              void* d_out, int out_size, void* d_ws, size_t ws_size,
                              hipStream_t stream)
{
    const float* logits = (const float*)d_in[0];
    const int*   labels = (const int*)d_in[1];
    const int n = in_sizes[1];  // 1,000,000 rows

    double* conf_sum = (double*)d_ws;
    double* acc_sum  = conf_sum + N_BINS;
    unsigned int* ticket = (unsigned int*)(acc_sum + N_BINS);

    // zero accumulators + ticket every call (graph-capture-safe)
    hipMemsetAsync(d_ws, 0, N_BINS * sizeof(double) * 2 + sizeof(unsigned int),
                   stream);

    const int blocks = 2048;  // 8 blocks/CU at 256 thr
    ece_fused<<<blocks, 256, 0, stream>>>(logits, labels, n,
                                          conf_sum, acc_sum, ticket,
                                          (float*)d_out);
}

// Round 7
// 114.016 us; speedup vs baseline: 1.6520x; 1.6520x over previous
//
#include <hip/hip_runtime.h>
#include <math.h>

#define N_BINS 15
#define LOG2E 1.4426950408889634f

// --- DPP helpers: full 16-lane butterfly with xor-span {1,2,7,15} ---
// 0xB1 = quad_perm[1,0,3,2] (xor1), 0x4E = quad_perm[2,3,0,1] (xor2),
// 0x141 = row_half_mirror (xor7), 0x140 = row_mirror (xor15).
template <int CTRL>
__device__ __forceinline__ float dpp_f(float x) {
    return __int_as_float(__builtin_amdgcn_update_dpp(
        0, __float_as_int(x), CTRL, 0xF, 0xF, true));
}
template <int CTRL>
__device__ __forceinline__ int dpp_i(int x) {
    return __builtin_amdgcn_update_dpp(0, x, CTRL, 0xF, 0xF, true);
}

__device__ __forceinline__ float rowmax16(float m) {
    m = fmaxf(m, dpp_f<0xB1>(m));
    m = fmaxf(m, dpp_f<0x4E>(m));
    m = fmaxf(m, dpp_f<0x141>(m));
    m = fmaxf(m, dpp_f<0x140>(m));
    return m;
}
__device__ __forceinline__ float rowsum16(float x) {
    x += dpp_f<0xB1>(x);
    x += dpp_f<0x4E>(x);
    x += dpp_f<0x141>(x);
    x += dpp_f<0x140>(x);
    return x;
}
__device__ __forceinline__ int rowmin16(int x) {
    x = min(x, dpp_i<0xB1>(x));
    x = min(x, dpp_i<0x4E>(x));
    x = min(x, dpp_i<0x141>(x));
    x = min(x, dpp_i<0x140>(x));
    return x;
}

// One row held by a 16-lane group; lane holds cols colbase..+3 and 64+colbase..+3.
__device__ __forceinline__ void process_row(
    float4 ca, float4 cb, int colbase, bool leader, int lab, bool valid,
    float* s_conf, float* s_acc)
{
    // row max: v_max3 tree + 4-step DPP
    const float t0 = fmaxf(fmaxf(ca.x, ca.y), ca.z);
    const float t1 = fmaxf(fmaxf(ca.w, cb.x), cb.y);
    const float t2 = fmaxf(fmaxf(cb.z, cb.w), t0);
    float m = fmaxf(t1, t2);
    m = rowmax16(m);

    // sum(exp2(v*log2e - m*log2e))
    const float nmL = -m * LOG2E;
    float e0 = __builtin_amdgcn_exp2f(fmaf(ca.x, LOG2E, nmL));
    float e1 = __builtin_amdgcn_exp2f(fmaf(ca.y, LOG2E, nmL));
    float e2 = __builtin_amdgcn_exp2f(fmaf(ca.z, LOG2E, nmL));
    float e3 = __builtin_amdgcn_exp2f(fmaf(ca.w, LOG2E, nmL));
    float e4 = __builtin_amdgcn_exp2f(fmaf(cb.x, LOG2E, nmL));
    float e5 = __builtin_amdgcn_exp2f(fmaf(cb.y, LOG2E, nmL));
    float e6 = __builtin_amdgcn_exp2f(fmaf(cb.z, LOG2E, nmL));
    float e7 = __builtin_amdgcn_exp2f(fmaf(cb.w, LOG2E, nmL));
    float e = ((e0 + e1) + (e2 + e3)) + ((e4 + e5) + (e6 + e7));
    e = rowsum16(e);

    // deferred argmax (first occurrence): candidate index or INF, min-reduce
    const int INF = 0x7FFFFFFF;
    const int c0 = (ca.x == m) ? colbase      : INF;
    const int c1 = (ca.y == m) ? colbase + 1  : INF;
    const int c2 = (ca.z == m) ? colbase + 2  : INF;
    const int c3 = (ca.w == m) ? colbase + 3  : INF;
    const int c4 = (cb.x == m) ? colbase + 64 : INF;
    const int c5 = (cb.y == m) ? colbase + 65 : INF;
    const int c6 = (cb.z == m) ? colbase + 66 : INF;
    const int c7 = (cb.w == m) ? colbase + 67 : INF;
    const int m1 = min(min(c0, c1), c2);
    const int m2 = min(min(c3, c4), c5);
    const int m3 = min(min(c6, c7), m1);
    int idx = min(m2, m3);
    idx = rowmin16(idx);

    if (valid && leader) {
        const float conf = __builtin_amdgcn_rcpf(e);
        int bin = (int)ceilf(conf * (float)N_BINS) - 1;
        bin = min(max(bin, 0), N_BINS - 1);
        atomicAdd(&s_conf[bin], conf);
        atomicAdd(&s_acc[bin], (idx == lab) ? 1.0f : 0.0f);
    }
}

// Round-4 proven loop (measured 127us total): 16 lanes/row, two 4-row tiles
// (8 rows) per wave per iteration, compiler-managed depth-1 prefetch, u32
// incremental byte addressing, branch-free main loop. Labels are ALSO
// prefetched one iteration ahead (round-4 loaded them in-iteration -> ~600cy
// stall on first-touch HBM lines). NO fused epilogue: rounds 5/6 showed the
// last-block ticket + __threadfence costs ~60us (device-scope fence = L2
// writeback on non-coherent-XCD gfx950, x2048 blocks).
__global__ __launch_bounds__(256) void ece_pass1(
    const float* __restrict__ logits,
    const int* __restrict__ labels,
    int n,
    double* __restrict__ conf_sum,
    double* __restrict__ acc_sum)
{
    __shared__ float s_conf[N_BINS];
    __shared__ float s_acc[N_BINS];

    const int t = threadIdx.x;
    if (t < N_BINS) { s_conf[t] = 0.f; s_acc[t] = 0.f; }
    __syncthreads();

    const int lane = t & 63;
    const int g    = lane >> 4;          // row within 4-row tile
    const int s    = lane & 15;          // sublane within 16-lane group
    const bool leader = (s == 0);
    const int colbase = 4 * s;

    const int wid = (blockIdx.x << 2) | (t >> 6);   // wave id
    const int nw  = gridDim.x << 2;                 // total waves
    const unsigned rstep = (unsigned)nw * 8u;       // rows per grid iteration
    const unsigned bstep = rstep * 512u;            // bytes per grid iteration

    // iterations where ALL 8 rows of this wave are < n
    int nfull = 0;
    {
        const int lim = n - 8 - wid * 8;
        if (lim >= 0) nfull = lim / (int)rstep + 1;
    }

    const char* __restrict__ Lg = (const char*)logits;
    const unsigned row0 = (unsigned)(wid * 8 + g);      // tile-A row, iter 0
    unsigned off  = row0 * 512u + (unsigned)s * 16u;    // tile-A byte offset
    unsigned lrow = row0;                               // label index

    float4 a0, a1, b0, b1;
    int labA = -1, labB = -1;
    if (nfull > 0) {
        a0 = *(const float4*)(Lg + off);
        a1 = *(const float4*)(Lg + off + 256u);
        b0 = *(const float4*)(Lg + off + 2048u);
        b1 = *(const float4*)(Lg + off + 2304u);
        labA = labels[lrow];
        labB = labels[lrow + 4u];
    }

    for (int k = 0; k < nfull; ++k) {
        const float4 ca0 = a0, ca1 = a1, cb0 = b0, cb1 = b1;
        const int clabA = labA, clabB = labB;

        const unsigned noff = off + bstep;
        if (k + 1 < nfull) {   // wave-uniform scalar branch
            a0 = *(const float4*)(Lg + noff);
            a1 = *(const float4*)(Lg + noff + 256u);
            b0 = *(const float4*)(Lg + noff + 2048u);
            b1 = *(const float4*)(Lg + noff + 2304u);
            labA = labels[lrow + rstep];
            labB = labels[lrow + rstep + 4u];
        }

        process_row(ca0, ca1, colbase, leader, clabA, true, s_conf, s_acc);
        process_row(cb0, cb1, colbase, leader, clabB, true, s_conf, s_acc);

        off = noff;
        lrow += rstep;
    }

    // generic guarded tail (at most one iteration; empty for n = 1e6)
    {
        const unsigned tbase = (unsigned)(wid * 8) + (unsigned)nfull * rstep;
        if (tbase < (unsigned)n) {
            const unsigned rA = tbase + (unsigned)g;
            const unsigned rB = rA + 4u;
            const bool vA = rA < (unsigned)n;
            const bool vB = rB < (unsigned)n;
            const unsigned cA = vA ? rA : (unsigned)(n - 1);
            const unsigned cB = vB ? rB : (unsigned)(n - 1);
            const unsigned oA = cA * 512u + (unsigned)s * 16u;
            const unsigned oB = cB * 512u + (unsigned)s * 16u;
            float4 ta0 = *(const float4*)(Lg + oA);
            float4 ta1 = *(const float4*)(Lg + oA + 256u);
            float4 tb0 = *(const float4*)(Lg + oB);
            float4 tb1 = *(const float4*)(Lg + oB + 256u);
            const int tlabA = vA ? labels[rA] : -1;
            const int tlabB = vB ? labels[rB] : -1;
            process_row(ta0, ta1, colbase, leader, tlabA, vA, s_conf, s_acc);
            process_row(tb0, tb1, colbase, leader, tlabB, vB, s_conf, s_acc);
        }
    }

    __syncthreads();
    // flush block-local histogram (conf>0 iff bin nonempty)
    if (t < N_BINS && s_conf[t] != 0.f) {
        atomicAdd(&conf_sum[t], (double)s_conf[t]);
        atomicAdd(&acc_sum[t], (double)s_acc[t]);
    }
}

// Pass 2: tiny scalar finish in f64. Counts cancel:
// sum_b gap_b * cnt_b / n == sum_b |conf_sum_b - acc_sum_b| / n,
// and empty bins contribute 0 automatically.
__global__ void ece_pass2(const double* __restrict__ conf_sum,
                          const double* __restrict__ acc_sum,
                          int n, float* __restrict__ out)
{
    double ece = 0.0;
    #pragma unroll
    for (int b = 0; b < N_BINS; ++b)
        ece += fabs(conf_sum[b] - acc_sum[b]);
    out[0] = (float)(ece / (double)n);
}

extern "C" void kernel_launch(void* const* d_in, const int* in_sizes, int n_in,
                              void* d_out, int out_size, void* d_ws, size_t ws_size,
                              hipStream_t stream)
{
    const float* logits = (const float*)d_in[0];
    const int*   labels = (const int*)d_in[1];
    const int n = in_sizes[1];  // 1,000,000 rows

    double* conf_sum = (double*)d_ws;
    double* acc_sum  = conf_sum + N_BINS;

    // zero accumulators every call (graph-capture-safe)
    hipMemsetAsync(d_ws, 0, N_BINS * sizeof(double) * 2, stream);

    const int blocks = 2048;  // 8 blocks/CU at 256 thr
    ece_pass1<<<blocks, 256, 0, stream>>>(logits, labels, n,
                                          conf_sum, acc_sum);
    ece_pass2<<<1, 1, 0, stream>>>(conf_sum, acc_sum, n, (float*)d_out);
}